// Round 6
// baseline (39.146 us; speedup 1.0000x reference)
//
#include <hip/hip_runtime.h>

// Lattice geometry (fixed by the reference problem)
constexpr int TD = 32, XD = 16, YD = 16, ZD = 16;
constexpr int NSITE  = TD * XD * YD * ZD;   // 131072
constexpr int PLANE  = NSITE * 3;           // 393216 float4s per batch plane
constexpr int NBATCH = 16;
constexpr int BPT    = 4;                   // batches per thread
constexpr int NGROUP = NBATCH / BPT;        // 4
constexpr int WPB    = 4;                   // waves per block (256 threads)

typedef float v4f __attribute__((ext_vector_type(4)));

__global__ __launch_bounds__(256) void qshift_kernel(
    const float* __restrict__ field,   // [B, site, 3, 4] = [B][PLANE] float4
    const float* __restrict__ gauge,   // [4, site, 3, 3]
    const int*   __restrict__ dir_p,
    float*       __restrict__ out)     // [B][PLANE] float4
{
    // wave-local staging: 64 own + 2 low-halo + 2 high-halo float4s, per batch
    __shared__ v4f stage[WPB][BPT][68];

    const int lane = threadIdx.x & 63;
    const int w    = threadIdx.x >> 6;
    const int jj   = blockIdx.x * 256 + threadIdx.x;   // [0, PLANE)
    const int b0   = blockIdx.y * BPT;
    const int dir  = *dir_p;                           // wave-uniform

    const v4f* f4 = (const v4f*)field;
    v4f*       o4 = (v4f*)out;

    if (dir == 0) {  // identity copy, dense
        #pragma unroll
        for (int k = 0; k < BPT; ++k) {
            const long idx = (long)(b0 + k) * PLANE + jj;
            o4[idx] = f4[idx];
        }
        return;
    }

    const int d     = (dir > 0) ? dir : -dir;          // 1..4
    const int a     = d - 1;                           // lattice axis
    const int shift = (a == 0) ? 12 : (a == 1) ? 8 : (a == 2) ? 4 : 0;
    const int len   = (a == 0) ? TD : 16;

    // source float4 index within a batch plane, for output float4 index j
    auto srcidx = [&](int j) -> int {
        const int s  = (int)((unsigned)j / 3u);
        const int cc = j - s * 3;
        const int ca = (s >> shift) & (len - 1);
        const int cs = (dir > 0) ? ((ca == 0) ? (len - 1) : (ca - 1))
                                 : ((ca == len - 1) ? 0 : (ca + 1));
        return (s + ((cs - ca) << shift)) * 3 + cc;
    };

    const int site = (int)((unsigned)jj / 3u);
    const int c    = jj - site * 3;
    const int ca   = (site >> shift) & (len - 1);
    const int cs   = (dir > 0) ? ((ca == 0) ? (len - 1) : (ca - 1))
                               : ((ca == len - 1) ? 0 : (ca + 1));
    const int ssite   = site + ((cs - ca) << shift);
    const int src_own = ssite * 3 + c;

    // gauge row for output color c (load once, reuse across BPT batches)
    const int gsite = (dir > 0) ? ssite : site;        // dagger(roll) vs plain
    const float* gp = gauge + ((long)a * NSITE + (long)gsite) * 9;
    float m0, m1, m2;
    if (dir > 0) { m0 = gp[c];     m1 = gp[3 + c];   m2 = gp[6 + c];   } // g^T row
    else         { m0 = gp[3 * c]; m1 = gp[3 * c + 1]; m2 = gp[3 * c + 2]; }

    // halo: lanes 0,1 -> slots 0,1 (j = wbase-2, wbase-1);
    //       lanes 2,3 -> slots 66,67 (j = wbase+64, wbase+65)
    int halo_slot = 0, src_halo = 0;
    if (lane < 4) {
        const int joff = (lane < 2) ? (lane - 2) : (62 + lane);  // -2,-1,64,65
        int jh = (jj - lane) + joff;                             // wbase + joff
        jh = (jh < 0) ? 0 : ((jh >= PLANE) ? (PLANE - 1) : jh);  // clamp (unused slots)
        halo_slot = (lane < 2) ? lane : (lane + 64);             // 0,1,66,67
        src_halo  = srcidx(jh);
    }

    // stage all BPT batches (independent global loads in flight)
    #pragma unroll
    for (int k = 0; k < BPT; ++k) {
        const long pb = (long)(b0 + k) * PLANE;
        stage[w][k][2 + lane] = f4[pb + src_own];
        if (lane < 4) stage[w][k][halo_slot] = f4[pb + src_halo];
    }

    // consume: lane's site occupies stage slots p..p+2 (p = lane + 2 - c)
    const int p = lane + 2 - c;
    #pragma unroll
    for (int k = 0; k < BPT; ++k) {
        const v4f f0 = stage[w][k][p];
        const v4f f1 = stage[w][k][p + 1];
        const v4f f2 = stage[w][k][p + 2];
        o4[(long)(b0 + k) * PLANE + jj] = m0 * f0 + m1 * f1 + m2 * f2;
    }
}

extern "C" void kernel_launch(void* const* d_in, const int* in_sizes, int n_in,
                              void* d_out, int out_size, void* d_ws, size_t ws_size,
                              hipStream_t stream) {
    const float* field = (const float*)d_in[0];
    const float* gauge = (const float*)d_in[1];
    const int*   dirp  = (const int*)d_in[2];
    float*       outp  = (float*)d_out;

    dim3 grid(PLANE / 256, NGROUP);   // (1536, 4)
    qshift_kernel<<<grid, 256, 0, stream>>>(field, gauge, dirp, outp);
}

// Round 7
// 36.722 us; speedup vs baseline: 1.0660x; 1.0660x over previous
//
#include <hip/hip_runtime.h>

// Lattice geometry (fixed by the reference problem)
constexpr int TD = 32, XD = 16, YD = 16, ZD = 16;
constexpr int NSITE  = TD * XD * YD * ZD;   // 131072
constexpr int PLANE  = NSITE * 3;           // 393216 float4s per batch plane
constexpr int NBATCH = 16;
constexpr int BPT    = 4;                   // batches per thread
constexpr int NGROUP = NBATCH / BPT;        // 4
constexpr int WPB    = 4;                   // waves per block (256 threads)

typedef float v4f __attribute__((ext_vector_type(4)));

__global__ __launch_bounds__(256) void qshift_kernel(
    const float* __restrict__ field,   // [B, site, 3, 4] = [B][PLANE] float4
    const float* __restrict__ gauge,   // [4, site, 3, 3]
    const int*   __restrict__ dir_p,
    float*       __restrict__ out)     // [B][PLANE] float4
{
    // wave-local staging: 64 own + 2 low-halo + 2 high-halo float4s, per batch
    __shared__ v4f stage[WPB][BPT][68];

    const int lane = threadIdx.x & 63;
    const int w    = threadIdx.x >> 6;
    const int jj   = blockIdx.x * 256 + threadIdx.x;   // [0, PLANE)
    const int b0   = blockIdx.y * BPT;
    const int dir  = *dir_p;                           // wave-uniform

    const v4f* f4 = (const v4f*)field;
    v4f*       o4 = (v4f*)out;

    if (dir == 0) {  // identity copy, dense
        #pragma unroll
        for (int k = 0; k < BPT; ++k) {
            const long idx = (long)(b0 + k) * PLANE + jj;
            __builtin_nontemporal_store(f4[idx], &o4[idx]);
        }
        return;
    }

    const int d     = (dir > 0) ? dir : -dir;          // 1..4
    const int a     = d - 1;                           // lattice axis
    const int shift = (a == 0) ? 12 : (a == 1) ? 8 : (a == 2) ? 4 : 0;
    const int len   = (a == 0) ? TD : 16;

    // source float4 index within a batch plane, for output float4 index j
    auto srcidx = [&](int j) -> int {
        const int s  = (int)((unsigned)j / 3u);
        const int cc = j - s * 3;
        const int ca = (s >> shift) & (len - 1);
        const int cs = (dir > 0) ? ((ca == 0) ? (len - 1) : (ca - 1))
                                 : ((ca == len - 1) ? 0 : (ca + 1));
        return (s + ((cs - ca) << shift)) * 3 + cc;
    };

    const int site = (int)((unsigned)jj / 3u);
    const int c    = jj - site * 3;
    const int ca   = (site >> shift) & (len - 1);
    const int cs   = (dir > 0) ? ((ca == 0) ? (len - 1) : (ca - 1))
                               : ((ca == len - 1) ? 0 : (ca + 1));
    const int ssite   = site + ((cs - ca) << shift);
    const int src_own = ssite * 3 + c;

    // gauge row for output color c (load once, reuse across BPT batches)
    const int gsite = (dir > 0) ? ssite : site;        // dagger(roll) vs plain
    const float* gp = gauge + ((long)a * NSITE + (long)gsite) * 9;
    float m0, m1, m2;
    if (dir > 0) { m0 = gp[c];     m1 = gp[3 + c];   m2 = gp[6 + c];   } // g^T row
    else         { m0 = gp[3 * c]; m1 = gp[3 * c + 1]; m2 = gp[3 * c + 2]; }

    // halo: lanes 0,1 -> slots 0,1 (j = wbase-2, wbase-1);
    //       lanes 2,3 -> slots 66,67 (j = wbase+64, wbase+65)
    int halo_slot = 0, src_halo = 0;
    if (lane < 4) {
        const int joff = (lane < 2) ? (lane - 2) : (62 + lane);  // -2,-1,64,65
        int jh = (jj - lane) + joff;                             // wbase + joff
        jh = (jh < 0) ? 0 : ((jh >= PLANE) ? (PLANE - 1) : jh);  // clamp (unused slots)
        halo_slot = (lane < 2) ? lane : (lane + 64);             // 0,1,66,67
        src_halo  = srcidx(jh);
    }

    // stage all BPT batches (independent global loads in flight)
    #pragma unroll
    for (int k = 0; k < BPT; ++k) {
        const long pb = (long)(b0 + k) * PLANE;
        stage[w][k][2 + lane] = f4[pb + src_own];
        if (lane < 4) stage[w][k][halo_slot] = f4[pb + src_halo];
    }

    // consume: lane's site occupies stage slots p..p+2 (p = lane + 2 - c)
    const int p = lane + 2 - c;
    #pragma unroll
    for (int k = 0; k < BPT; ++k) {
        const v4f f0 = stage[w][k][p];
        const v4f f1 = stage[w][k][p + 1];
        const v4f f2 = stage[w][k][p + 2];
        const v4f o  = m0 * f0 + m1 * f1 + m2 * f2;
        __builtin_nontemporal_store(o, &o4[(long)(b0 + k) * PLANE + jj]);
    }
}

extern "C" void kernel_launch(void* const* d_in, const int* in_sizes, int n_in,
                              void* d_out, int out_size, void* d_ws, size_t ws_size,
                              hipStream_t stream) {
    const float* field = (const float*)d_in[0];
    const float* gauge = (const float*)d_in[1];
    const int*   dirp  = (const int*)d_in[2];
    float*       outp  = (float*)d_out;

    dim3 grid(PLANE / 256, NGROUP);   // (1536, 4)
    qshift_kernel<<<grid, 256, 0, stream>>>(field, gauge, dirp, outp);
}